// Round 4
// baseline (173.433 us; speedup 1.0000x reference)
//
#include <hip/hip_runtime.h>
#include <stdint.h>

// Problem constants (B,C,D,H,W) = (2,1,128,256,256)
#define BB 2
#define DD 128
#define HH 256
#define WW 256
static constexpr int64_t N = (int64_t)BB * DD * HH * WW;   // 16,777,216
static constexpr int WPR    = WW / 64;                     // 4 words per row
static constexpr int NROWS  = BB * DD * HH;                // 65,536 rows
static constexpr int K1_BLOCKS = NROWS / 4;                // 16384 blocks, 1 row/wave
static constexpr int K2_BLOCKS = (HH / 16) * (DD / 16) * (BB * WPR); // 1024
static constexpr int ROWS_PER_K2 = NROWS / K2_BLOCKS;      // 64

// ---------------------------------------------------------------------------
// K1: predicate + X-dilation + base L1 row-sum. One wave = one row (max
// dispatch parallelism — R1's 16384-block shape was the fastest measured;
// R3 showed deeper per-wave MLP only loses occupancy against the ~3.1 TB/s
// read-path ceiling). Ballot -> 4 uniform 64-bit words, X-dilation is pure
// SALU. Per-wave f32 partial straight to p0f[row]; no LDS, no syncthreads.
// Mask layout: word c of a row has bit l = voxel 4l+c.
// ---------------------------------------------------------------------------
__global__ __launch_bounds__(256) void mask_xdil_sum(const float* __restrict__ tgt,
                                                     const float* __restrict__ inp,
                                                     uint64_t* __restrict__ mask,
                                                     float* __restrict__ p0f,
                                                     unsigned* __restrict__ counter) {
    const int wave = threadIdx.x >> 6;
    const int lane = threadIdx.x & 63;
    const int row  = blockIdx.x * 4 + wave;

    if (blockIdx.x == 0 && threadIdx.x == 0) *counter = 0u;   // re-arm ticket

    const int64_t base = (int64_t)row * WW;
    const float4 t = ((const float4*)(tgt + base))[lane];
    const float4 a = ((const float4*)(inp + base))[lane];

    float s = fabsf(t.x - a.x) + fabsf(t.y - a.y)
            + fabsf(t.z - a.z) + fabsf(t.w - a.w);

    const uint64_t b0 = __ballot(t.x > 0.0f && t.x < 1.0f);
    const uint64_t b1 = __ballot(t.y > 0.0f && t.y < 1.0f);
    const uint64_t b2 = __ballot(t.z > 0.0f && t.z < 1.0f);
    const uint64_t b3 = __ballot(t.w > 0.0f && t.w < 1.0f);

    const uint64_t U  = b0 | b1 | b2 | b3;
    const uint64_t d0 = U | ((b1 | b2 | b3) << 1);
    const uint64_t d1 = U | ((b2 | b3) << 1) | (b0 >> 1);
    const uint64_t d2 = U | (b3 << 1) | ((b0 | b1) >> 1);
    const uint64_t d3 = U | ((b0 | b1 | b2) >> 1);

    const uint64_t dv = (lane & 2) ? ((lane & 1) ? d3 : d2)
                                   : ((lane & 1) ? d1 : d0);
    if (lane < 4)
        mask[(int64_t)row * WPR + lane] = dv;   // one 32B coalesced store/wave

    #pragma unroll
    for (int off = 32; off > 0; off >>= 1)
        s += __shfl_down(s, off, 64);
    if (lane == 0) p0f[row] = s;
}

// ---------------------------------------------------------------------------
// K2: fused Y+Z dilation + residual + IN-KERNEL FINALIZE (ticket pattern).
// Block = 16x16 (y,z) words for fixed (b,wx). Raw 22x22 halo -> y-dilate ->
// z-dilate into register word v. loss*N = 11*S0 - 10*SA. All-ones words
// (overwhelmingly common) issue ZERO data loads; zero bits fetch only their
// voxels (voxel = 4*bit + wx). Each block folds its 64-row slice of p0f
// (parallel across wave 0's lanes) with its residual into ONE agent-scope
// partial STORE (no hot single-address atomicAdd — that serialization was
// R3's +21us regression). Last block by ticket reduces the 1024 partials.
// ---------------------------------------------------------------------------
__global__ __launch_bounds__(256) void yz_dil_reduce(const uint64_t* __restrict__ in,
                                                     const float* __restrict__ inp,
                                                     const float* __restrict__ tgt,
                                                     const float* __restrict__ p0f,
                                                     double* __restrict__ p1,
                                                     unsigned* __restrict__ counter,
                                                     float* __restrict__ out) {
    __shared__ uint64_t raw[22][23];   // +1 pad
    __shared__ uint64_t yd[22][17];    // +1 pad
    const int ty = threadIdx.x & 15;
    const int tz = threadIdx.x >> 4;
    const int y0 = blockIdx.x * 16;
    const int z0 = blockIdx.y * 16;
    const int b  = blockIdx.z >> 2;
    const int wx = blockIdx.z & 3;
    const int lane = threadIdx.x & 63;
    const int wv   = threadIdx.x >> 6;
    const int flat = blockIdx.x + gridDim.x * (blockIdx.y + gridDim.y * blockIdx.z);

    for (int idx = threadIdx.x; idx < 22 * 22; idx += 256) {
        const int zz = idx / 22, yy = idx % 22;
        const int gz = z0 - 3 + zz, gy = y0 - 3 + yy;
        uint64_t v = 0;
        if (gz >= 0 && gz < DD && gy >= 0 && gy < HH)
            v = in[(((int64_t)(b * DD + gz)) * HH + gy) * WPR + wx];
        raw[zz][yy] = v;
    }
    __syncthreads();

    for (int idx = threadIdx.x; idx < 22 * 16; idx += 256) {
        const int zz = idx >> 4, yy = idx & 15;
        uint64_t v = 0;
        #pragma unroll
        for (int d = 0; d < 7; d++) v |= raw[zz][yy + d];
        yd[zz][yy] = v;
    }
    __syncthreads();

    uint64_t v = 0;
    #pragma unroll
    for (int d = 0; d < 7; d++) v |= yd[tz + d][ty];

    // residual: |t-i| at voxels whose dilated mask bit is 0 (rare/never)
    float sab = 0.0f;
    if (v != ~0ull) {
        uint64_t z = ~v;
        const int64_t vox = (((int64_t)(b * DD + z0 + tz)) * HH + y0 + ty) * WW + wx;
        while (z) {
            const int l = __ffsll((unsigned long long)z) - 1;
            z &= z - 1;
            const int64_t o = vox + 4 * (int64_t)l;   // voxel = 4*bit + wx
            sab += fabsf(tgt[o] - inp[o]);
        }
    }

    #pragma unroll
    for (int off = 32; off > 0; off >>= 1)
        sab += __shfl_down(sab, off, 64);
    __shared__ float ws[4];
    __shared__ int lastflag;
    if (lane == 0) ws[wv] = sab;
    __syncthreads();

    // wave 0: parallel fold of this block's 64 p0f row-partials + ticket
    if (wv == 0) {
        double s0 = (double)p0f[flat * ROWS_PER_K2 + lane];
        #pragma unroll
        for (int off = 32; off > 0; off >>= 1)
            s0 += __shfl_down(s0, off, 64);
        int lf = 0;
        if (lane == 0) {
            const double sa = (double)((ws[0] + ws[1]) + (ws[2] + ws[3]));
            const double contrib = 11.0 * s0 - 10.0 * sa;
            __hip_atomic_store(&p1[flat], contrib, __ATOMIC_RELEASE,
                               __HIP_MEMORY_SCOPE_AGENT);
            const unsigned tk = __hip_atomic_fetch_add(counter, 1u, __ATOMIC_ACQ_REL,
                                                       __HIP_MEMORY_SCOPE_AGENT);
            lf = (tk == (unsigned)(K2_BLOCKS - 1)) ? 1 : 0;
        }
        if (threadIdx.x == 0) lastflag = lf;
    }
    __syncthreads();

    // last block: parallel reduction of the 1024 partials (agent-scope loads)
    if (lastflag) {
        __threadfence();
        double acc = 0.0;
        for (int i = threadIdx.x; i < K2_BLOCKS; i += 256)
            acc += __hip_atomic_load(&p1[i], __ATOMIC_RELAXED,
                                     __HIP_MEMORY_SCOPE_AGENT);
        #pragma unroll
        for (int off = 32; off > 0; off >>= 1)
            acc += __shfl_down(acc, off, 64);
        __shared__ double wd[4];
        if (lane == 0) wd[wv] = acc;
        __syncthreads();
        if (threadIdx.x == 0)
            out[0] = (float)(((wd[0] + wd[1]) + (wd[2] + wd[3])) / (double)N);
    }
}

extern "C" void kernel_launch(void* const* d_in, const int* in_sizes, int n_in,
                              void* d_out, int out_size, void* d_ws, size_t ws_size,
                              hipStream_t stream) {
    const float* inp = (const float*)d_in[0];   // "input"
    const float* tgt = (const float*)d_in[1];   // "target"
    float* out = (float*)d_out;

    // workspace layout (every region fully written each run; no poison reads)
    float*    p0f     = (float*)d_ws;                           // 65536 f32 = 256 KB
    double*   p1      = (double*)((char*)d_ws + 256 * 1024);    // 1024 doubles = 8 KB
    unsigned* counter = (unsigned*)((char*)d_ws + 272 * 1024);  // 4 B
    uint64_t* mask0   = (uint64_t*)((char*)d_ws + 512 * 1024);  // 2 MB

    mask_xdil_sum<<<K1_BLOCKS, 256, 0, stream>>>(tgt, inp, mask0, p0f, counter);
    yz_dil_reduce<<<dim3(HH / 16, DD / 16, BB * WPR), 256, 0, stream>>>(
        mask0, inp, tgt, p0f, p1, counter, out);
}

// Round 5
// 146.388 us; speedup vs baseline: 1.1848x; 1.1848x over previous
//
#include <hip/hip_runtime.h>
#include <stdint.h>

// Problem constants (B,C,D,H,W) = (2,1,128,256,256)
#define BB 2
#define DD 128
#define HH 256
#define WW 256
static constexpr int64_t N = (int64_t)BB * DD * HH * WW;   // 16,777,216
static constexpr int WPR    = WW / 64;                     // 4 words per row
static constexpr int NROWS  = BB * DD * HH;                // 65,536 rows
static constexpr int K1_BLOCKS = NROWS / 4;                // 16384 blocks, 1 row/wave
static constexpr int K2_BLOCKS = (HH / 16) * (DD / 16) * (BB * WPR); // 1024
static constexpr int ROWS_PER_K2 = NROWS / K2_BLOCKS;      // 64

// ---------------------------------------------------------------------------
// K1: predicate + X-dilation + base L1 row-sum. One wave = one row — the
// fastest of six measured structural variants (40.4us; deeper per-wave MLP,
// fewer blocks, and shuffle-packing all measured equal or worse against the
// ~3.3 TB/s read-path floor; cache-resident replay is equally slow, so the
// pass is read-path-bound, not traffic-bound). Ballot -> 4 uniform 64-bit
// words; X-dilation is pure SALU. Per-wave f32 partial straight to
// p0f[row]; no LDS, no syncthreads, no atomics.
// Mask layout: word c of a row has bit l = voxel 4l+c.
// ---------------------------------------------------------------------------
__global__ __launch_bounds__(256) void mask_xdil_sum(const float* __restrict__ tgt,
                                                     const float* __restrict__ inp,
                                                     uint64_t* __restrict__ mask,
                                                     float* __restrict__ p0f) {
    const int wave = threadIdx.x >> 6;
    const int lane = threadIdx.x & 63;
    const int row  = blockIdx.x * 4 + wave;

    const int64_t base = (int64_t)row * WW;
    const float4 t = ((const float4*)(tgt + base))[lane];
    const float4 a = ((const float4*)(inp + base))[lane];

    float s = fabsf(t.x - a.x) + fabsf(t.y - a.y)
            + fabsf(t.z - a.z) + fabsf(t.w - a.w);

    const uint64_t b0 = __ballot(t.x > 0.0f && t.x < 1.0f);
    const uint64_t b1 = __ballot(t.y > 0.0f && t.y < 1.0f);
    const uint64_t b2 = __ballot(t.z > 0.0f && t.z < 1.0f);
    const uint64_t b3 = __ballot(t.w > 0.0f && t.w < 1.0f);

    const uint64_t U  = b0 | b1 | b2 | b3;
    const uint64_t d0 = U | ((b1 | b2 | b3) << 1);
    const uint64_t d1 = U | ((b2 | b3) << 1) | (b0 >> 1);
    const uint64_t d2 = U | (b3 << 1) | ((b0 | b1) >> 1);
    const uint64_t d3 = U | ((b0 | b1 | b2) >> 1);

    const uint64_t dv = (lane & 2) ? ((lane & 1) ? d3 : d2)
                                   : ((lane & 1) ? d1 : d0);
    if (lane < 4)
        mask[(int64_t)row * WPR + lane] = dv;   // one 32B coalesced store/wave

    #pragma unroll
    for (int off = 32; off > 0; off >>= 1)
        s += __shfl_down(s, off, 64);
    if (lane == 0) p0f[row] = s;
}

// ---------------------------------------------------------------------------
// K2: fused Y+Z dilation (radius 3 each) + residual + p0 fold. NO atomics,
// NO threadfence, NO cross-block sync — R3/R4 measured the in-kernel
// finalize (agent-scope acq_rel / ticket) at +25-30us from per-block cache
// flushes; a separate 2us launch is strictly cheaper.
// Block = 16x16 (y,z) words for fixed (b,wx). Raw 22x22 halo -> y-dilate ->
// z-dilate into register word v. loss*N = 11*S0 - 10*SA. All-ones words
// (overwhelmingly common) issue ZERO data loads; zero bits fetch only
// their voxels (voxel = 4*bit + wx). Each block writes ONE double:
// contrib = 11*S0_slice - 10*SA_block (plain store).
// ---------------------------------------------------------------------------
__global__ __launch_bounds__(256) void yz_dil_reduce(const uint64_t* __restrict__ in,
                                                     const float* __restrict__ inp,
                                                     const float* __restrict__ tgt,
                                                     const float* __restrict__ p0f,
                                                     double* __restrict__ p1) {
    __shared__ uint64_t raw[22][23];   // +1 pad
    __shared__ uint64_t yd[22][17];    // +1 pad
    const int ty = threadIdx.x & 15;
    const int tz = threadIdx.x >> 4;
    const int y0 = blockIdx.x * 16;
    const int z0 = blockIdx.y * 16;
    const int b  = blockIdx.z >> 2;
    const int wx = blockIdx.z & 3;
    const int lane = threadIdx.x & 63;
    const int wv   = threadIdx.x >> 6;
    const int flat = blockIdx.x + gridDim.x * (blockIdx.y + gridDim.y * blockIdx.z);

    for (int idx = threadIdx.x; idx < 22 * 22; idx += 256) {
        const int zz = idx / 22, yy = idx % 22;
        const int gz = z0 - 3 + zz, gy = y0 - 3 + yy;
        uint64_t v = 0;
        if (gz >= 0 && gz < DD && gy >= 0 && gy < HH)
            v = in[(((int64_t)(b * DD + gz)) * HH + gy) * WPR + wx];
        raw[zz][yy] = v;
    }
    __syncthreads();

    for (int idx = threadIdx.x; idx < 22 * 16; idx += 256) {
        const int zz = idx >> 4, yy = idx & 15;
        uint64_t v = 0;
        #pragma unroll
        for (int d = 0; d < 7; d++) v |= raw[zz][yy + d];
        yd[zz][yy] = v;
    }
    __syncthreads();

    uint64_t v = 0;
    #pragma unroll
    for (int d = 0; d < 7; d++) v |= yd[tz + d][ty];

    // residual: |t-i| at voxels whose dilated mask bit is 0 (rare/never)
    float sab = 0.0f;
    if (v != ~0ull) {
        uint64_t z = ~v;
        const int64_t vox = (((int64_t)(b * DD + z0 + tz)) * HH + y0 + ty) * WW + wx;
        while (z) {
            const int l = __ffsll((unsigned long long)z) - 1;
            z &= z - 1;
            const int64_t o = vox + 4 * (int64_t)l;   // voxel = 4*bit + wx
            sab += fabsf(tgt[o] - inp[o]);
        }
    }

    #pragma unroll
    for (int off = 32; off > 0; off >>= 1)
        sab += __shfl_down(sab, off, 64);
    __shared__ float ws[4];
    if (lane == 0) ws[wv] = sab;
    __syncthreads();

    // wave 0: parallel fold of this block's 64 p0f row-partials (plain loads)
    if (wv == 0) {
        double s0 = (double)p0f[flat * ROWS_PER_K2 + lane];
        #pragma unroll
        for (int off = 32; off > 0; off >>= 1)
            s0 += __shfl_down(s0, off, 64);
        if (lane == 0) {
            const double sa = (double)((ws[0] + ws[1]) + (ws[2] + ws[3]));
            p1[flat] = 11.0 * s0 - 10.0 * sa;
        }
    }
}

// ---------------------------------------------------------------------------
// K3: sum the 1024 block contributions; out = total / N.
// ---------------------------------------------------------------------------
__global__ __launch_bounds__(256) void finalize(const double* __restrict__ p1,
                                                float* __restrict__ out) {
    double s = 0.0;
    for (int i = threadIdx.x; i < K2_BLOCKS; i += 256) s += p1[i];
    #pragma unroll
    for (int off = 32; off > 0; off >>= 1)
        s += __shfl_down(s, off, 64);
    __shared__ double wd[4];
    const int lane = threadIdx.x & 63;
    const int wv   = threadIdx.x >> 6;
    if (lane == 0) wd[wv] = s;
    __syncthreads();
    if (threadIdx.x == 0)
        out[0] = (float)(((wd[0] + wd[1]) + (wd[2] + wd[3])) / (double)N);
}

extern "C" void kernel_launch(void* const* d_in, const int* in_sizes, int n_in,
                              void* d_out, int out_size, void* d_ws, size_t ws_size,
                              hipStream_t stream) {
    const float* inp = (const float*)d_in[0];   // "input"
    const float* tgt = (const float*)d_in[1];   // "target"
    float* out = (float*)d_out;

    // workspace layout (every region fully written each run; no poison reads)
    float*    p0f   = (float*)d_ws;                           // 65536 f32 = 256 KB
    double*   p1    = (double*)((char*)d_ws + 256 * 1024);    // 1024 doubles = 8 KB
    uint64_t* mask0 = (uint64_t*)((char*)d_ws + 512 * 1024);  // 2 MB

    mask_xdil_sum<<<K1_BLOCKS, 256, 0, stream>>>(tgt, inp, mask0, p0f);
    yz_dil_reduce<<<dim3(HH / 16, DD / 16, BB * WPR), 256, 0, stream>>>(
        mask0, inp, tgt, p0f, p1);
    finalize<<<1, 256, 0, stream>>>(p1, out);
}